// Round 5
// baseline (383.871 us; speedup 1.0000x reference)
//
#include <hip/hip_runtime.h>

#define N_BATCH 8192
#define S 14
#define N_CELLS (N_BATCH * S * S)     // 1,605,632 cells
#define FPC 30
#define TILE 64                       // cells per tile (one wave, 1 cell/lane)
#define TILE_BYTES (TILE * FPC * 4)   // 7680 B per tensor per tile
#define N_TILES (N_CELLS / TILE)      // 25088
#define GRID 2560                     // 10 one-wave blocks per CU (LDS-limited)

// Round-5 structure: async DMA staging via global_load_lds (coalesced 1024B
// per instr, no VGPR round-trip, no park-phase lgkm serialization), single
// LDS buffer, overlap purely via TLP (10 waves/CU; each wave ~94% of its
// cycle has 15.4KB in flight -> ~145KB outstanding per CU >> the ~9KB
// Little's-law requirement for 6.3 TB/s). Rounds 0/1/4 all capped at
// ~2.7-3.0 TB/s effective with identifiable per-wave drain serialization;
// this removes all of it.
__global__ __launch_bounds__(64) void yolo_loss_kernel(
    const float* __restrict__ pred, const float* __restrict__ targ,
    float* __restrict__ out)
{
    __shared__ char sp[TILE_BYTES];   // pred tile image (contiguous, as in HBM)
    __shared__ char st[TILE_BYTES];   // targ tile image

    const int lane = threadIdx.x;     // 0..63
    const float INV14 = 1.0f / 14.0f;
    float acc = 0.0f;

    for (int tile = blockIdx.x; tile < N_TILES; tile += GRID) {
        // Fence: previous iteration's ds_reads (LDS is written in-function,
        // so the clobber DOES order them) stay above; DMA writes stay below.
        asm volatile("" ::: "memory");

        {
            const char* gp = reinterpret_cast<const char*>(pred) + (size_t)tile * TILE_BYTES;
            const char* gt = reinterpret_cast<const char*>(targ) + (size_t)tile * TILE_BYTES;
            // 7680 B per tensor = 7 full-wave 16B DMAs (1024 B each) + 1
            // half-wave 16B DMA (512 B, lanes 0..31; exec never empty so the
            // instruction always issues). LDS dest is wave-uniform base +
            // lane*16 -> linear image identical to global layout.
#pragma unroll
            for (int c = 0; c < 7; ++c) {
                __builtin_amdgcn_global_load_lds(
                    (const __attribute__((address_space(1))) void*)(gp + c * 1024 + lane * 16),
                    (__attribute__((address_space(3))) void*)(sp + c * 1024), 16, 0, 0);
                __builtin_amdgcn_global_load_lds(
                    (const __attribute__((address_space(1))) void*)(gt + c * 1024 + lane * 16),
                    (__attribute__((address_space(3))) void*)(st + c * 1024), 16, 0, 0);
            }
            if (lane < 32) {
                __builtin_amdgcn_global_load_lds(
                    (const __attribute__((address_space(1))) void*)(gp + 7 * 1024 + lane * 16),
                    (__attribute__((address_space(3))) void*)(sp + 7 * 1024), 16, 0, 0);
                __builtin_amdgcn_global_load_lds(
                    (const __attribute__((address_space(1))) void*)(gt + 7 * 1024 + lane * 16),
                    (__attribute__((address_space(3))) void*)(st + 7 * 1024), 16, 0, 0);
            }
        }

        // Drain this tile's DMAs; sched_barrier stops the machine scheduler
        // hoisting the ds_reads above the wait (rule #18).
        asm volatile("s_waitcnt vmcnt(0)" ::: "memory");
        __builtin_amdgcn_sched_barrier(0);

        // ---- compute: lane owns cell (tile*64 + lane), 30 floats at lane*120 ----
        float p[FPC], t[FPC];
        {
            const float2* p2 = reinterpret_cast<const float2*>(sp) + lane * 15;
            const float2* t2 = reinterpret_cast<const float2*>(st) + lane * 15;
#pragma unroll
            for (int i = 0; i < 15; ++i) {
                const float2 a = p2[i]; p[2 * i] = a.x; p[2 * i + 1] = a.y;
                const float2 b = t2[i]; t[2 * i] = b.x; t[2 * i + 1] = b.y;
            }
        }

        const float objf = (t[4] > 0.0f) ? 1.0f : 0.0f;
        const float noof = 1.0f - objf;

        // no-object confidence loss (conf indices 4, 9)
        const float d4 = p[4] - t[4];
        const float d9 = p[9] - t[9];
        const float nooobj = noof * (d4 * d4 + d9 * d9);

        // target box (target boxes duplicated; t[5..8] unused by reference)
        const float tx = t[0] * INV14, ty = t[1] * INV14;
        const float tw = t[2], th = t[3];
        const float tx1 = tx - 0.5f * tw, ty1 = ty - 0.5f * th;
        const float tx2 = tx + 0.5f * tw, ty2 = ty + 0.5f * th;
        const float area_t = (tx2 - tx1) * (ty2 - ty1);

        float iou[2];
#pragma unroll
        for (int b = 0; b < 2; ++b) {
            const float px = p[5 * b + 0] * INV14, py = p[5 * b + 1] * INV14;
            const float pw = p[5 * b + 2], ph = p[5 * b + 3];
            const float px1 = px - 0.5f * pw, py1 = py - 0.5f * ph;
            const float px2 = px + 0.5f * pw, py2 = py + 0.5f * ph;
            const float ltx = fmaxf(px1, tx1), lty = fmaxf(py1, ty1);
            const float rbx = fminf(px2, tx2), rby = fminf(py2, ty2);
            const float wx = fmaxf(rbx - ltx, 0.0f);
            const float wy = fmaxf(rby - lty, 0.0f);
            const float inter = wx * wy;
            const float area_p = (px2 - px1) * (py2 - py1);
            iou[b] = inter / (area_p + area_t - inter);
        }

        // responsible box: jnp.argmax -> ties pick box 0
        const bool r1 = (iou[1] > iou[0]);
        const float max_iou = fmaxf(iou[0], iou[1]);

        const float pc  = r1 ? p[9] : p[4];
        const float pnc = r1 ? p[4] : p[9];
        const float contain = objf * (pc - max_iou) * (pc - max_iou);
        const float not_contain = objf * pnc * pnc;

        const float rx = r1 ? p[5] : p[0];
        const float ry = r1 ? p[6] : p[1];
        const float rw = r1 ? p[7] : p[2];
        const float rh = r1 ? p[8] : p[3];
        const float dx = rx - t[0];
        const float dy = ry - t[1];
        const float dw = sqrtf(rw) - sqrtf(t[2]);
        const float dh = sqrtf(rh) - sqrtf(t[3]);
        const float loc = objf * (dx * dx + dy * dy + dw * dw + dh * dh);

        float cls = 0.0f;
#pragma unroll
        for (int k = 10; k < 30; ++k) {
            const float d = p[k] - t[k];
            cls += d * d;
        }
        cls *= objf;

        acc += 5.0f * loc + 2.0f * contain + 0.5f * nooobj + cls + not_contain;
    }

    acc *= (1.0f / (float)N_BATCH);

    // ---- 64-lane wave reduction -> one atomic per block (2560 total) ----
#pragma unroll
    for (int off = 32; off > 0; off >>= 1)
        acc += __shfl_down(acc, off, 64);

    if (lane == 0)
        atomicAdd(out, acc);
}

extern "C" void kernel_launch(void* const* d_in, const int* in_sizes, int n_in,
                              void* d_out, int out_size, void* d_ws, size_t ws_size,
                              hipStream_t stream) {
    const float* pred = (const float*)d_in[0];
    const float* targ = (const float*)d_in[1];
    float* out = (float*)d_out;

    hipMemsetAsync(out, 0, sizeof(float), stream);

    yolo_loss_kernel<<<GRID, 64, 0, stream>>>(pred, targ, out);
}